// Round 1
// baseline (359.875 us; speedup 1.0000x reference)
//
#include <hip/hip_runtime.h>

// ---------------------------------------------------------------- types
typedef __attribute__((ext_vector_type(8))) short bf16x8;   // 8 bf16 (4 VGPR)
typedef __attribute__((ext_vector_type(4))) float f32x4;
typedef __attribute__((ext_vector_type(2))) unsigned int u32x2;

#define MFMA16(a, b, c) __builtin_amdgcn_mfma_f32_16x16x32_bf16((a), (b), (c), 0, 0, 0)

// B=4, S=2048, E=1024, H=16, D=64
#define S_LEN 2048
#define NHEAD 16
#define DHEAD 64
#define EMB   1024
#define BH    64            // B*H
#define MROWS 8192          // B*S

__device__ __forceinline__ unsigned short f2bf(float f) {
  unsigned int u = __builtin_bit_cast(unsigned int, f);
  u += 0x7FFFu + ((u >> 16) & 1u);          // round-to-nearest-even
  return (unsigned short)(u >> 16);
}

__device__ __forceinline__ void gl_lds16(const void* g, void* l) {
  __builtin_amdgcn_global_load_lds(
      (const __attribute__((address_space(1))) void*)g,
      (__attribute__((address_space(3))) void*)l, 16, 0, 0);
}

// ---------------------------------------------------------------- cast fp32 -> bf16
__global__ __launch_bounds__(256) void cast_bf16(const float* __restrict__ src,
                                                 unsigned short* __restrict__ dst, int n) {
  int i = (blockIdx.x * 256 + threadIdx.x) * 4;
  if (i + 3 < n) {
    f32x4 v = *(const f32x4*)(src + i);
    unsigned long long pk =
        (unsigned long long)f2bf(v[0]) |
        ((unsigned long long)f2bf(v[1]) << 16) |
        ((unsigned long long)f2bf(v[2]) << 32) |
        ((unsigned long long)f2bf(v[3]) << 48);
    *(unsigned long long*)(dst + i) = pk;
  }
}

// ---------------------------------------------------------------- transpose + cast: src[R][C] fp32 -> dst[C][R] bf16
__global__ __launch_bounds__(256) void transpose_cast(const float* __restrict__ src,
                                                      unsigned short* __restrict__ dst,
                                                      int R, int C) {
  __shared__ float tile[32][33];
  int c0 = blockIdx.x * 32, r0 = blockIdx.y * 32;
  int tx = threadIdx.x, ty = threadIdx.y;   // block (32,8)
  for (int i = 0; i < 32; i += 8)
    tile[ty + i][tx] = src[(size_t)(r0 + ty + i) * C + c0 + tx];
  __syncthreads();
  for (int i = 0; i < 32; i += 8)
    dst[(size_t)(c0 + ty + i) * R + r0 + tx] = f2bf(tile[tx][ty + i]);
}

// ---------------------------------------------------------------- GEMM core (m97 structure)
// C[128x128] per block, BK=32, 4 waves 2x2, each wave 64x64 = 4x4 MFMA tiles.
// A: [M x 1024] bf16 row-major. Bt: [N x 1024] bf16 row-major (i.e. B transposed).
#define GEMM_CORE(A_, Bt_)                                                              \
  __shared__ unsigned short As[128 * 32];                                               \
  __shared__ unsigned short Bs[128 * 32];                                               \
  const int tid = threadIdx.x;                                                          \
  const int w = tid >> 6, lane = tid & 63, l15 = lane & 15, quad = lane >> 4;           \
  const int wm = w >> 1, wn = w & 1;                                                    \
  const int col0 = blockIdx.x * 128, row0 = blockIdx.y * 128;                           \
  f32x4 acc[4][4] = {};                                                                 \
  for (int kt = 0; kt < 32; ++kt) {                                                     \
    const int k0 = kt * 32;                                                             \
    for (int p = 0; p < 2; ++p) {                                                       \
      int c = p * 256 + tid;                                                            \
      int m = c >> 2, k8 = (c & 3) * 8;                                                 \
      void* ldsA = (char*)As + (size_t)(p * 256 + (tid & 192)) * 16;                    \
      void* ldsB = (char*)Bs + (size_t)(p * 256 + (tid & 192)) * 16;                    \
      gl_lds16(A_ + (size_t)(row0 + m) * 1024 + k0 + k8, ldsA);                         \
      gl_lds16(Bt_ + (size_t)(col0 + m) * 1024 + k0 + k8, ldsB);                        \
    }                                                                                   \
    __syncthreads();                                                                    \
    bf16x8 af[4], bf[4];                                                                \
    for (int i = 0; i < 4; ++i)                                                         \
      af[i] = *(const bf16x8*)&As[(wm * 64 + i * 16 + l15) * 32 + quad * 8];            \
    for (int j = 0; j < 4; ++j)                                                         \
      bf[j] = *(const bf16x8*)&Bs[(wn * 64 + j * 16 + l15) * 32 + quad * 8];            \
    for (int i = 0; i < 4; ++i)                                                         \
      for (int j = 0; j < 4; ++j)                                                       \
        acc[i][j] = MFMA16(af[i], bf[j], acc[i][j]);                                    \
    __syncthreads();                                                                    \
  }

// GEMM1: qkv = Xbf @ Wqkv + bqkv, scattered to per-head Q/K/V buffers:
// dst layout: [(bh)*3 + which][s][d], bf16.
__global__ __launch_bounds__(256) void gemm_qkv(const unsigned short* __restrict__ A,
                                                const unsigned short* __restrict__ Bt,
                                                const float* __restrict__ bias,
                                                unsigned short* __restrict__ qkvout) {
  GEMM_CORE(A, Bt)
  for (int i = 0; i < 4; ++i) {
    int grow = row0 + wm * 64 + i * 16 + quad * 4;
    for (int j = 0; j < 4; ++j) {
      int gcol = col0 + wn * 64 + j * 16 + l15;          // 0..3071
      float bv = bias[gcol];
      unsigned int h = (unsigned)gcol / 192u;
      unsigned int rr = (unsigned)gcol % 192u;
      unsigned int which = rr >> 6, d = rr & 63u;
      for (int r = 0; r < 4; ++r) {
        int row = grow + r;
        int b = row >> 11, s = row & 2047;
        size_t dst = ((((size_t)b * NHEAD + h) * 3 + which) * S_LEN + s) * DHEAD + d;
        qkvout[dst] = f2bf(acc[i][j][r] + bv);
      }
    }
  }
}

// GEMM2: out = Attn @ Wo + bo (fp32 out). Attn buffer [b][h][s][d] == [8192][1024] row-major.
__global__ __launch_bounds__(256) void gemm_out(const unsigned short* __restrict__ A,
                                                const unsigned short* __restrict__ Bt,
                                                const float* __restrict__ bias,
                                                float* __restrict__ out) {
  GEMM_CORE(A, Bt)
  for (int i = 0; i < 4; ++i) {
    int grow = row0 + wm * 64 + i * 16 + quad * 4;
    for (int j = 0; j < 4; ++j) {
      int gcol = col0 + wn * 64 + j * 16 + l15;
      float bv = bias[gcol];
      for (int r = 0; r < 4; ++r)
        out[(size_t)(grow + r) * 1024 + gcol] = acc[i][j][r] + bv;
    }
  }
}

// ---------------------------------------------------------------- flash attention
// grid (BH, S/64). Block 256 = 4 waves; wave w owns q-rows [q0+16w, q0+16w+16).
// K-tile 64 keys. Online softmax, causal.
__global__ __launch_bounds__(256) void attn_kernel(const unsigned short* __restrict__ qkv,
                                                   unsigned short* __restrict__ attnout) {
  __shared__ unsigned short Ks[64 * 72];    // [s_k][d] padded stride 72
  __shared__ unsigned int Vts[64 * 34];     // [d][s2] pairs (s,s+1), stride 34 u32
  __shared__ unsigned short Ps[4 * 16 * 72]; // per-wave P tile [m][k], stride 72

  const int tid = threadIdx.x;
  const int w = tid >> 6, lane = tid & 63, l15 = lane & 15, quad = lane >> 4;
  const int bh = blockIdx.x;
  const int qt = blockIdx.y;
  const int q0 = qt * 64;

  const unsigned short* Qg = qkv + ((size_t)bh * 3 + 0) * S_LEN * DHEAD;
  const unsigned short* Kg = qkv + ((size_t)bh * 3 + 1) * S_LEN * DHEAD;
  const unsigned short* Vg = qkv + ((size_t)bh * 3 + 2) * S_LEN * DHEAD;

  // Q fragments, held in registers for the whole K-loop. A-frag: m=l15, k=quad*8+j.
  bf16x8 qf0, qf1;
  {
    const unsigned short* p = Qg + (size_t)(q0 + w * 16 + l15) * DHEAD + quad * 8;
    qf0 = *(const bf16x8*)p;
    qf1 = *(const bf16x8*)(p + 32);
  }

  f32x4 oacc[4] = {};              // d-tiles, C-layout rows quad*4+r
  float m_i[4], l_i[4];
  for (int r = 0; r < 4; ++r) { m_i[r] = -1e30f; l_i[r] = 0.f; }
  const float scale = 0.125f;      // 1/sqrt(64)

  for (int kt = 0; kt <= qt; ++kt) {
    const int k0 = kt * 64;
    // ---- stage K tile (padded)
    {
      const unsigned short* src = Kg + (size_t)k0 * DHEAD;
      for (int p = 0; p < 2; ++p) {
        int c = p * 256 + tid;
        int row = c >> 3, col8 = (c & 7) * 8;
        bf16x8 v = *(const bf16x8*)(src + row * 64 + col8);
        *(bf16x8*)&Ks[row * 72 + col8] = v;
      }
      // ---- stage V transposed: thread reads rows (2*s2, 2*s2+1), 8 d each
      const unsigned short* vs = Vg + (size_t)k0 * DHEAD;
      int d0 = (tid & 7) * 8, s2 = tid >> 3;
      bf16x8 va = *(const bf16x8*)(vs + (2 * s2) * 64 + d0);
      bf16x8 vb = *(const bf16x8*)(vs + (2 * s2 + 1) * 64 + d0);
      for (int jj = 0; jj < 8; ++jj) {
        unsigned int u = (unsigned int)(unsigned short)va[jj] |
                         ((unsigned int)(unsigned short)vb[jj] << 16);
        Vts[(d0 + jj) * 34 + s2] = u;
      }
    }
    __syncthreads();

    // ---- S = Q K^T  (wave: 16 q-rows x 64 k-cols)
    f32x4 sacc[4] = {};
    for (int j = 0; j < 4; ++j) {
      const unsigned short* kb = &Ks[(j * 16 + l15) * 72 + quad * 8];
      bf16x8 b0 = *(const bf16x8*)kb;
      bf16x8 b1 = *(const bf16x8*)(kb + 32);
      sacc[j] = MFMA16(qf0, b0, sacc[j]);
      sacc[j] = MFMA16(qf1, b1, sacc[j]);
    }

    // ---- mask + online softmax (C-layout: row = quad*4+r, col = l15)
    float p_val[4][4];   // [j][r]
    for (int r = 0; r < 4; ++r) {
      const int qrow = q0 + w * 16 + quad * 4 + r;
      float mx = -1e30f;
      for (int j = 0; j < 4; ++j) {
        float sv = sacc[j][r] * scale;
        int kcol = k0 + j * 16 + l15;
        if (kcol > qrow) sv = -1e30f;
        p_val[j][r] = sv;
        mx = fmaxf(mx, sv);
      }
      for (int off = 1; off < 16; off <<= 1)
        mx = fmaxf(mx, __shfl_xor(mx, off));
      float mnew = fmaxf(m_i[r], mx);
      float alpha = __expf(m_i[r] - mnew);
      float rsum = 0.f;
      for (int j = 0; j < 4; ++j) {
        float e = __expf(p_val[j][r] - mnew);
        p_val[j][r] = e;
        rsum += e;
      }
      for (int off = 1; off < 16; off <<= 1)
        rsum += __shfl_xor(rsum, off);
      l_i[r] = l_i[r] * alpha + rsum;
      m_i[r] = mnew;
      for (int dt = 0; dt < 4; ++dt) oacc[dt][r] *= alpha;
    }

    // ---- P: C-layout -> LDS -> A-layout (per-wave tile, no barrier needed)
    unsigned short* pw = &Ps[w * 16 * 72];
    for (int j = 0; j < 4; ++j)
      for (int r = 0; r < 4; ++r)
        pw[(quad * 4 + r) * 72 + j * 16 + l15] = f2bf(p_val[j][r]);

    bf16x8 pf0 = *(const bf16x8*)&pw[l15 * 72 + quad * 8];
    bf16x8 pf1 = *(const bf16x8*)&pw[l15 * 72 + 32 + quad * 8];

    // ---- O += P V   (B-frag from transposed V tile)
    for (int dt = 0; dt < 4; ++dt) {
      const unsigned int* vp = &Vts[(dt * 16 + l15) * 34];
      union { unsigned int u[4]; bf16x8 s; } cv0, cv1;
      u32x2 a0 = *(const u32x2*)(vp + quad * 4);
      u32x2 a1 = *(const u32x2*)(vp + quad * 4 + 2);
      cv0.u[0] = a0[0]; cv0.u[1] = a0[1]; cv0.u[2] = a1[0]; cv0.u[3] = a1[1];
      u32x2 b0 = *(const u32x2*)(vp + 16 + quad * 4);
      u32x2 b1 = *(const u32x2*)(vp + 16 + quad * 4 + 2);
      cv1.u[0] = b0[0]; cv1.u[1] = b0[1]; cv1.u[2] = b1[0]; cv1.u[3] = b1[1];
      oacc[dt] = MFMA16(pf0, cv0.s, oacc[dt]);
      oacc[dt] = MFMA16(pf1, cv1.s, oacc[dt]);
    }
    __syncthreads();
  }

  // ---- normalize + store (bf16, natural [bh][s][d] layout)
  for (int r = 0; r < 4; ++r) {
    float inv = 1.f / l_i[r];
    int qrow = q0 + w * 16 + quad * 4 + r;
    unsigned short* dst = attnout + ((size_t)bh * S_LEN + qrow) * DHEAD;
    for (int dt = 0; dt < 4; ++dt)
      dst[dt * 16 + l15] = f2bf(oacc[dt][r] * inv);
  }
}

// ---------------------------------------------------------------- launch
extern "C" void kernel_launch(void* const* d_in, const int* in_sizes, int n_in,
                              void* d_out, int out_size, void* d_ws, size_t ws_size,
                              hipStream_t stream) {
  const float* x    = (const float*)d_in[0];
  // d_in[1] = mask: deterministic tril, causality applied analytically
  const float* Wqkv = (const float*)d_in[2];
  const float* bqkv = (const float*)d_in[3];
  const float* Wo   = (const float*)d_in[4];
  const float* bo   = (const float*)d_in[5];
  float* out = (float*)d_out;

  char* ws = (char*)d_ws;
  unsigned short* Xbf   = (unsigned short*)(ws);                 // 16 MB
  unsigned short* WqkvT = (unsigned short*)(ws + 16777216);      // 6 MB
  unsigned short* WoT   = (unsigned short*)(ws + 23068672);      // 2 MB
  unsigned short* QKV   = (unsigned short*)(ws + 25165824);      // 48 MB
  unsigned short* Attn  = (unsigned short*)(ws + 75497472);      // 16 MB

  cast_bf16<<<8192, 256, 0, stream>>>(x, Xbf, MROWS * EMB);
  transpose_cast<<<dim3(96, 32), dim3(32, 8), 0, stream>>>(Wqkv, WqkvT, 1024, 3072);
  transpose_cast<<<dim3(32, 32), dim3(32, 8), 0, stream>>>(Wo, WoT, 1024, 1024);
  gemm_qkv<<<dim3(24, 64), 256, 0, stream>>>(Xbf, WqkvT, bqkv, QKV);
  attn_kernel<<<dim3(BH, S_LEN / 64), 256, 0, stream>>>(QKV, Attn);
  gemm_out<<<dim3(8, 64), 256, 0, stream>>>(Attn, WoT, bo, out);
}

// Round 2
// 322.708 us; speedup vs baseline: 1.1152x; 1.1152x over previous
//
#include <hip/hip_runtime.h>

// ---------------------------------------------------------------- types
typedef __attribute__((ext_vector_type(8))) short bf16x8;   // 8 bf16 (4 VGPR)
typedef __attribute__((ext_vector_type(4))) float f32x4;
typedef __attribute__((ext_vector_type(2))) unsigned int u32x2;

#define MFMA16(a, b, c) __builtin_amdgcn_mfma_f32_16x16x32_bf16((a), (b), (c), 0, 0, 0)

// B=4, S=2048, E=1024, H=16, D=64
#define S_LEN 2048
#define NHEAD 16
#define DHEAD 64
#define BH    64            // B*H
#define MROWS 8192          // B*S

__device__ __forceinline__ unsigned short f2bf(float f) {
  unsigned int u = __builtin_bit_cast(unsigned int, f);
  u += 0x7FFFu + ((u >> 16) & 1u);          // round-to-nearest-even
  return (unsigned short)(u >> 16);
}

__device__ __forceinline__ void gl_lds16(const void* g, void* l) {
  __builtin_amdgcn_global_load_lds(
      (const __attribute__((address_space(1))) void*)g,
      (__attribute__((address_space(3))) void*)l, 16, 0, 0);
}

// ---------------------------------------------------------------- cast fp32 -> bf16
__global__ __launch_bounds__(256) void cast_bf16(const float* __restrict__ src,
                                                 unsigned short* __restrict__ dst, int n) {
  int i = (blockIdx.x * 256 + threadIdx.x) * 4;
  if (i + 3 < n) {
    f32x4 v = *(const f32x4*)(src + i);
    unsigned long long pk =
        (unsigned long long)f2bf(v[0]) |
        ((unsigned long long)f2bf(v[1]) << 16) |
        ((unsigned long long)f2bf(v[2]) << 32) |
        ((unsigned long long)f2bf(v[3]) << 48);
    *(unsigned long long*)(dst + i) = pk;
  }
}

// ---------------------------------------------------------------- transpose + cast
__global__ __launch_bounds__(256) void transpose_cast(const float* __restrict__ src,
                                                      unsigned short* __restrict__ dst,
                                                      int R, int C) {
  __shared__ float tile[32][33];
  int c0 = blockIdx.x * 32, r0 = blockIdx.y * 32;
  int tx = threadIdx.x, ty = threadIdx.y;   // block (32,8)
  for (int i = 0; i < 32; i += 8)
    tile[ty + i][tx] = src[(size_t)(r0 + ty + i) * C + c0 + tx];
  __syncthreads();
  for (int i = 0; i < 32; i += 8)
    dst[(size_t)(c0 + ty + i) * R + r0 + tx] = f2bf(tile[tx][ty + i]);
}

// ---------------------------------------------------------------- GEMM core (m97 structure)
#define GEMM_CORE(A_, Bt_)                                                              \
  __shared__ unsigned short As[128 * 32];                                               \
  __shared__ unsigned short Bs[128 * 32];                                               \
  const int tid = threadIdx.x;                                                          \
  const int w = tid >> 6, lane = tid & 63, l15 = lane & 15, quad = lane >> 4;           \
  const int wm = w >> 1, wn = w & 1;                                                    \
  const int col0 = blockIdx.x * 128, row0 = blockIdx.y * 128;                           \
  f32x4 acc[4][4] = {};                                                                 \
  for (int kt = 0; kt < 32; ++kt) {                                                     \
    const int k0 = kt * 32;                                                             \
    for (int p = 0; p < 2; ++p) {                                                       \
      int c = p * 256 + tid;                                                            \
      int m = c >> 2, k8 = (c & 3) * 8;                                                 \
      void* ldsA = (char*)As + (size_t)(p * 256 + (tid & 192)) * 16;                    \
      void* ldsB = (char*)Bs + (size_t)(p * 256 + (tid & 192)) * 16;                    \
      gl_lds16(A_ + (size_t)(row0 + m) * 1024 + k0 + k8, ldsA);                         \
      gl_lds16(Bt_ + (size_t)(col0 + m) * 1024 + k0 + k8, ldsB);                        \
    }                                                                                   \
    __syncthreads();                                                                    \
    bf16x8 af[4], bfr[4];                                                               \
    for (int i = 0; i < 4; ++i)                                                         \
      af[i] = *(const bf16x8*)&As[(wm * 64 + i * 16 + l15) * 32 + quad * 8];            \
    for (int j = 0; j < 4; ++j)                                                         \
      bfr[j] = *(const bf16x8*)&Bs[(wn * 64 + j * 16 + l15) * 32 + quad * 8];           \
    for (int i = 0; i < 4; ++i)                                                         \
      for (int j = 0; j < 4; ++j)                                                       \
        acc[i][j] = MFMA16(af[i], bfr[j], acc[i][j]);                                   \
    __syncthreads();                                                                    \
  }

// GEMM1: qkv = Xbf @ Wqkv + bqkv. Q scaled by 0.125 (exact), K natural, V transposed [bh][d][s].
__global__ __launch_bounds__(256) void gemm_qkv(const unsigned short* __restrict__ A,
                                                const unsigned short* __restrict__ Bt,
                                                const float* __restrict__ bias,
                                                unsigned short* __restrict__ Qb,
                                                unsigned short* __restrict__ Kb,
                                                unsigned short* __restrict__ Vtb) {
  GEMM_CORE(A, Bt)
  for (int i = 0; i < 4; ++i) {
    int grow = row0 + wm * 64 + i * 16 + quad * 4;
    int b = grow >> 11, s = grow & 2047;
    for (int j = 0; j < 4; ++j) {
      int gcol = col0 + wn * 64 + j * 16 + l15;          // 0..3071
      float bv = bias[gcol];
      unsigned int h = (unsigned)gcol / 192u;
      unsigned int rr = (unsigned)gcol % 192u;
      unsigned int which = rr >> 6, d = rr & 63u;
      int bh = b * NHEAD + (int)h;
      if (which == 2u) {
        // V transposed: Vtb[bh][d][s], 4 s-consecutive values packed into one b64 store
        unsigned long long pk =
            (unsigned long long)f2bf(acc[i][j][0] + bv) |
            ((unsigned long long)f2bf(acc[i][j][1] + bv) << 16) |
            ((unsigned long long)f2bf(acc[i][j][2] + bv) << 32) |
            ((unsigned long long)f2bf(acc[i][j][3] + bv) << 48);
        *(unsigned long long*)(Vtb + ((size_t)bh * DHEAD + d) * S_LEN + s) = pk;
      } else {
        unsigned short* dst = (which == 0u ? Qb : Kb) + ((size_t)bh * S_LEN + s) * DHEAD + d;
        float qs = (which == 0u) ? 0.125f : 1.0f;   // fold 1/sqrt(D) into Q (exact pow2)
        for (int r = 0; r < 4; ++r)
          dst[(size_t)r * DHEAD] = f2bf((acc[i][j][r] + bv) * qs);
      }
    }
  }
}

// GEMM2: out = Attn @ Wo + bo (fp32 out). Attn flat [bh][s][d] == reshape quirk layout.
__global__ __launch_bounds__(256) void gemm_out(const unsigned short* __restrict__ A,
                                                const unsigned short* __restrict__ Bt,
                                                const float* __restrict__ bias,
                                                float* __restrict__ out) {
  GEMM_CORE(A, Bt)
  for (int i = 0; i < 4; ++i) {
    int grow = row0 + wm * 64 + i * 16 + quad * 4;
    for (int j = 0; j < 4; ++j) {
      int gcol = col0 + wn * 64 + j * 16 + l15;
      float bv = bias[gcol];
      for (int r = 0; r < 4; ++r)
        out[(size_t)(grow + r) * 1024 + gcol] = acc[i][j][r] + bv;
    }
  }
}

// ---------------------------------------------------------------- flash attention (S^T formulation)
// 1024 blocks 1D (heavy qt first). Block: 4 waves, 128 q-rows (wave w: rows q0+32w..+32, 2 subtiles).
// Per K-tile of 64: S^T = K·Q^T via MFMA (A=K rows, B=Q) -> softmax along register dim ->
// P [q][k] through per-wave LDS (b64 writes) -> O += P·V with V^T-staged B-frags.
__global__ __launch_bounds__(256) void attn_kernel(const unsigned short* __restrict__ Qb,
                                                   const unsigned short* __restrict__ Kb,
                                                   const unsigned short* __restrict__ Vtb,
                                                   unsigned short* __restrict__ attnout) {
  __shared__ unsigned short Ks[64 * 72];     // [k_row][d] stride 72
  __shared__ unsigned short Vts[64 * 72];    // [d][key]   stride 72
  __shared__ unsigned short Ps[4][32 * 72];  // per wave: [q_local 0..31][key] stride 72
  __shared__ float Abc[4][32];               // per wave alpha / l broadcast

  const int tid = threadIdx.x;
  const int w = tid >> 6, lane = tid & 63, l15 = lane & 15, quad = lane >> 4;
  const int bid = blockIdx.x;
  const int qt = 15 - (bid >> 6);            // heavy tiles dispatched first
  const int bh = bid & 63;
  const int q0 = qt * 128;

  const unsigned short* Qg = Qb + (size_t)bh * S_LEN * DHEAD;
  const unsigned short* Kg = Kb + (size_t)bh * S_LEN * DHEAD;
  const unsigned short* Vg = Vtb + (size_t)bh * DHEAD * S_LEN;

  // Q B-frags (n = q = l15, k = d = quad*8+j), held for whole kernel
  bf16x8 qf[2][2];
  for (int sub = 0; sub < 2; ++sub) {
    const unsigned short* p = Qg + (size_t)(q0 + w * 32 + sub * 16 + l15) * DHEAD + quad * 8;
    qf[sub][0] = *(const bf16x8*)p;
    qf[sub][1] = *(const bf16x8*)(p + 32);
  }

  f32x4 oacc[2][4] = {};                     // C-layout: row q = quad*4+r, col d = l15 (+16*dt)
  float m_i[2] = {-3e38f, -3e38f}, l_i[2] = {0.f, 0.f};

  unsigned short* Pw = Ps[w];
  float* Aw = Abc[w];
  const int fragoff = l15 * 72 + quad * 8;   // shorts

  const int ktfull = 2 * qt;
  for (int kt = 0; kt < ktfull + 2; ++kt) {
    const int k0 = kt * 64;
    // ---- stage K [k][d] and V^T [d][k] (each thread: 2 b128 loads + 2 b128 LDS writes)
    {
      int r0_ = tid >> 3, c0_ = (tid & 7) * 8;
      int r1_ = r0_ + 32;
      bf16x8 ka = *(const bf16x8*)(Kg + (size_t)(k0 + r0_) * 64 + c0_);
      bf16x8 kb = *(const bf16x8*)(Kg + (size_t)(k0 + r1_) * 64 + c0_);
      bf16x8 va = *(const bf16x8*)(Vg + (size_t)r0_ * S_LEN + k0 + c0_);
      bf16x8 vb = *(const bf16x8*)(Vg + (size_t)r1_ * S_LEN + k0 + c0_);
      *(bf16x8*)&Ks[r0_ * 72 + c0_] = ka;
      *(bf16x8*)&Ks[r1_ * 72 + c0_] = kb;
      *(bf16x8*)&Vts[r0_ * 72 + c0_] = va;
      *(bf16x8*)&Vts[r1_ * 72 + c0_] = vb;
    }
    __syncthreads();

    const bool pA = (kt == ktfull);
    const bool pB = (kt == ktfull + 1);
    const bool wact = !pB || (w >= 2);

    if (wact) {
      bf16x8 pf[2][2];
      #pragma unroll
      for (int sub = 0; sub < 2; ++sub) {
        const int jklim = pA ? (2 * w + sub) : (pB ? (2 * w + sub - 4) : 3);
        const bool diag = pA || pB;
        // ---- S^T: sacc[jk] rows k=jk*16+quad*4+r, col q=l15
        f32x4 sacc[4];
        #pragma unroll
        for (int jk = 0; jk < 4; ++jk) {
          if (jk <= jklim) {
            bf16x8 kf0 = *(const bf16x8*)&Ks[jk * 1152 + fragoff];
            bf16x8 kf1 = *(const bf16x8*)&Ks[jk * 1152 + 32 + fragoff];
            f32x4 z = {};
            z = MFMA16(kf0, qf[sub][0], z);
            z = MFMA16(kf1, qf[sub][1], z);
            if (diag && jk == jklim) {        // diagonal 16x16: mask key>query
              #pragma unroll
              for (int r = 0; r < 4; ++r)
                if (quad * 4 + r > l15) z[r] = -3e38f;
            }
            sacc[jk] = z;
          }
        }
        // ---- online softmax (reduction over register dim + 2 cross-quad shuffles)
        float mx = -3e38f;
        #pragma unroll
        for (int jk = 0; jk < 4; ++jk)
          if (jk <= jklim)
            mx = fmaxf(mx, fmaxf(fmaxf(sacc[jk][0], sacc[jk][1]),
                                 fmaxf(sacc[jk][2], sacc[jk][3])));
        mx = fmaxf(mx, __shfl_xor(mx, 16));
        mx = fmaxf(mx, __shfl_xor(mx, 32));
        float mnew = fmaxf(m_i[sub], mx);
        float alpha = __expf(m_i[sub] - mnew);
        m_i[sub] = mnew;
        float rsum = 0.f;
        #pragma unroll
        for (int jk = 0; jk < 4; ++jk) {
          unsigned int* pdst = (unsigned int*)&Pw[sub * 1152 + l15 * 72 + jk * 16 + quad * 4];
          if (jk <= jklim) {
            float e0 = __expf(sacc[jk][0] - mnew), e1 = __expf(sacc[jk][1] - mnew);
            float e2 = __expf(sacc[jk][2] - mnew), e3 = __expf(sacc[jk][3] - mnew);
            rsum += (e0 + e1) + (e2 + e3);
            unsigned int u0 = ((__builtin_bit_cast(unsigned int, e0) + 0x8000u) >> 16) |
                              ((__builtin_bit_cast(unsigned int, e1) + 0x8000u) & 0xFFFF0000u);
            unsigned int u1 = ((__builtin_bit_cast(unsigned int, e2) + 0x8000u) >> 16) |
                              ((__builtin_bit_cast(unsigned int, e3) + 0x8000u) & 0xFFFF0000u);
            *(u32x2*)pdst = (u32x2){u0, u1};
          } else {
            *(u32x2*)pdst = (u32x2){0u, 0u};
          }
        }
        rsum += __shfl_xor(rsum, 16);
        rsum += __shfl_xor(rsum, 32);
        l_i[sub] = l_i[sub] * alpha + rsum;
        // alpha broadcast to C-layout rows, rescale O
        Aw[sub * 16 + l15] = alpha;
        f32x4 a4 = *(const f32x4*)&Aw[sub * 16 + quad * 4];
        #pragma unroll
        for (int dt = 0; dt < 4; ++dt) oacc[sub][dt] *= a4;
        // P A-frags
        pf[sub][0] = *(const bf16x8*)&Pw[sub * 1152 + fragoff];
        pf[sub][1] = *(const bf16x8*)&Pw[sub * 1152 + 32 + fragoff];
      }
      // ---- O += P·V  (V B-frags shared across both subtiles)
      #pragma unroll
      for (int dt = 0; dt < 4; ++dt) {
        bf16x8 vb0 = *(const bf16x8*)&Vts[dt * 1152 + fragoff];
        bf16x8 vb1 = *(const bf16x8*)&Vts[dt * 1152 + 32 + fragoff];
        oacc[0][dt] = MFMA16(pf[0][0], vb0, oacc[0][dt]);
        oacc[0][dt] = MFMA16(pf[0][1], vb1, oacc[0][dt]);
        oacc[1][dt] = MFMA16(pf[1][0], vb0, oacc[1][dt]);
        oacc[1][dt] = MFMA16(pf[1][1], vb1, oacc[1][dt]);
      }
    }
    __syncthreads();
  }

  // ---- normalize + store (bf16, flat [bh][s][d])
  #pragma unroll
  for (int sub = 0; sub < 2; ++sub) {
    Aw[sub * 16 + l15] = l_i[sub];
    f32x4 l4 = *(const f32x4*)&Aw[sub * 16 + quad * 4];
    int qbase = q0 + w * 32 + sub * 16 + quad * 4;
    unsigned short* dst = attnout + ((size_t)bh * S_LEN + qbase) * DHEAD;
    #pragma unroll
    for (int r = 0; r < 4; ++r) {
      float inv = __builtin_amdgcn_rcpf(l4[r]);
      #pragma unroll
      for (int dt = 0; dt < 4; ++dt)
        dst[(size_t)r * DHEAD + dt * 16 + l15] = f2bf(oacc[sub][dt][r] * inv);
    }
  }
}

// ---------------------------------------------------------------- launch
extern "C" void kernel_launch(void* const* d_in, const int* in_sizes, int n_in,
                              void* d_out, int out_size, void* d_ws, size_t ws_size,
                              hipStream_t stream) {
  const float* x    = (const float*)d_in[0];
  // d_in[1] = mask: deterministic tril, causality applied analytically
  const float* Wqkv = (const float*)d_in[2];
  const float* bqkv = (const float*)d_in[3];
  const float* Wo   = (const float*)d_in[4];
  const float* bo   = (const float*)d_in[5];
  float* out = (float*)d_out;

  char* ws = (char*)d_ws;
  unsigned short* Xbf   = (unsigned short*)(ws);                 // 16 MB
  unsigned short* WqkvT = (unsigned short*)(ws + 16777216);      // 6 MB
  unsigned short* WoT   = (unsigned short*)(ws + 23068672);      // 2 MB
  unsigned short* Qb    = (unsigned short*)(ws + 25165824);      // 16.78 MB
  unsigned short* Kb    = (unsigned short*)(ws + 41943040);      // 16.78 MB
  unsigned short* Vtb   = (unsigned short*)(ws + 58720256);      // 16.78 MB
  unsigned short* Attn  = (unsigned short*)(ws + 75497472);      // 16.78 MB

  cast_bf16<<<8192, 256, 0, stream>>>(x, Xbf, MROWS * 1024);
  transpose_cast<<<dim3(96, 32), dim3(32, 8), 0, stream>>>(Wqkv, WqkvT, 1024, 3072);
  transpose_cast<<<dim3(32, 32), dim3(32, 8), 0, stream>>>(Wo, WoT, 1024, 1024);
  gemm_qkv<<<dim3(24, 64), 256, 0, stream>>>(Xbf, WqkvT, bqkv, Qb, Kb, Vtb);
  attn_kernel<<<1024, 256, 0, stream>>>(Qb, Kb, Vtb, Attn);
  gemm_out<<<dim3(8, 64), 256, 0, stream>>>(Attn, WoT, bo, out);
}